// Round 3
// baseline (1057.676 us; speedup 1.0000x reference)
//
#include <hip/hip_runtime.h>
#include <hip/hip_bf16.h>
#include <math.h>

#define N_NODES 50000
#define D_FEAT  128
#define HIDDEN  256
#define CLASSES 40
#define N_EDGES 800000

typedef unsigned int  u32;
typedef unsigned short u16;

__device__ __forceinline__ float bf_lo(u32 w) { union { u32 i; float f; } u; u.i = w << 16; return u.f; }
__device__ __forceinline__ float bf_hi(u32 w) { union { u32 i; float f; } u; u.i = w & 0xffff0000u; return u.f; }
__device__ __forceinline__ u16 f2bf(float f) {
  union { float f; u32 i; } u; u.f = f; u32 i = u.i;
  return (u16)((i + 0x7fffu + ((i >> 16) & 1u)) >> 16);  // RNE
}
__device__ __forceinline__ u32 packbf(float a, float b) { return (u32)f2bf(a) | ((u32)f2bf(b) << 16); }

// ---- kernel 0: probe edge_index storage dtype (int64 vs int32) -------------
// 256 int64-interpreted samples; max byte offset 6.375MB < 6.4MB (safe if i32).
__global__ void detect_kernel(const long long* __restrict__ e64, int* __restrict__ flag) {
  __shared__ int ok;
  if (threadIdx.x == 0) ok = 1;
  __syncthreads();
  long long v = e64[(size_t)threadIdx.x * 3125];
  if (v < 0 || v >= N_NODES) ok = 0;
  __syncthreads();
  if (threadIdx.x == 0) *flag = ok;  // 1 => int64 storage
}

// ---- kernel 1: decode edges to int32 src/dst + degree histogram ------------
__global__ __launch_bounds__(256) void convert_hist_kernel(
    const void* __restrict__ eraw, const int* __restrict__ flag,
    int* __restrict__ src, int* __restrict__ dst, int* __restrict__ counts) {
  int e = blockIdx.x * 256 + threadIdx.x;
  int s, d;
  if (*flag) {
    const long long* p = (const long long*)eraw;
    s = (int)p[e]; d = (int)p[N_EDGES + e];
  } else {
    const int* p = (const int*)eraw;
    s = p[e]; d = p[N_EDGES + e];
  }
  // defensive: invalid ids become self-skipped edges (no ws corruption)
  if ((u32)s >= N_NODES || (u32)d >= N_NODES) { s = -1; d = -1; }
  src[e] = s; dst[e] = d;
  if (d >= 0) atomicAdd(counts + d, 1);
}

// ---- kernel 2: exclusive scan of counts -> offsets[N+1], cursor copy -------
__global__ __launch_bounds__(1024) void prefix_kernel(
    const int* __restrict__ counts, int* __restrict__ offsets, int* __restrict__ cursor) {
  __shared__ int lds[1024];
  const int t = threadIdx.x;
  const int CH = 49;  // 1024*49 >= 50000
  int b = t * CH, e = min(b + CH, N_NODES);
  int s = 0;
  for (int i = b; i < e; i++) s += counts[i];
  lds[t] = s;
  __syncthreads();
  for (int d = 1; d < 1024; d <<= 1) {
    int v = (t >= d) ? lds[t - d] : 0;
    __syncthreads();
    lds[t] += v;
    __syncthreads();
  }
  int run = lds[t] - s;  // exclusive prefix of this chunk
  for (int i = b; i < e; i++) { offsets[i] = run; cursor[i] = run; run += counts[i]; }
  if (t == 1023) offsets[N_NODES] = lds[1023];
}

// ---- kernel 3: scatter edges into CSR-by-dst -------------------------------
__global__ __launch_bounds__(256) void scatter_kernel(
    const int* __restrict__ src, const int* __restrict__ dst,
    int* __restrict__ cursor, int* __restrict__ csr_src) {
  int e = blockIdx.x * 256 + threadIdx.x;
  int d = dst[e];
  if (d < 0) return;
  int pos = atomicAdd(cursor + d, 1);
  csr_src[pos] = src[e];
}

// ---- kernel 4: layer-1 mean aggregation (gather), wave per node, f32 -------
__global__ __launch_bounds__(256) void gather1_kernel(
    const float* __restrict__ x, const int* __restrict__ offsets,
    const int* __restrict__ csr_src, float* __restrict__ agg1) {
  const int node = blockIdx.x * 4 + (threadIdx.x >> 6);
  const int lane = threadIdx.x & 63;
  int b = offsets[node], e = offsets[node + 1];
  float a0 = 0.f, a1 = 0.f;
  for (int i = b; i < e; i++) {
    int s = csr_src[i];
    float2 v = ((const float2*)(x + (size_t)s * D_FEAT))[lane];
    a0 += v.x; a1 += v.y;
  }
  float inv = 1.0f / (float)max(e - b, 1);
  float2 o; o.x = a0 * inv; o.y = a1 * inv;
  ((float2*)(agg1 + (size_t)node * D_FEAT))[lane] = o;
}

// ---- kernel 5: layer-1 GEMM (VALU, f32)  h = relu(agg1@Wl1^T + x@Wr1^T + b)
// block = 16 rows x 256 cols; 256 thr; thread tile 4 rows x 4 cols.
__global__ __launch_bounds__(256) void gemm1_kernel(
    const float* __restrict__ agg1, const float* __restrict__ x,
    const float* __restrict__ Wl1, const float* __restrict__ Wr1,
    const float* __restrict__ bl1, u16* __restrict__ h) {
  __shared__ float A_lds[16 * D_FEAT];  // 8KB, one phase at a time
  const int t  = threadIdx.x;
  const int tx = t & 63;   // col group: cols tx*4 .. tx*4+3
  const int ty = t >> 6;   // row group: rows ty*4 .. ty*4+3 (wave-uniform)
  const int m0 = blockIdx.x * 16;

  float acc[4][4];
  #pragma unroll
  for (int i = 0; i < 4; i++)
    #pragma unroll
    for (int j = 0; j < 4; j++) acc[i][j] = 0.f;

  for (int ph = 0; ph < 2; ph++) {
    const float* A = (ph == 0 ? agg1 : x) + (size_t)m0 * D_FEAT;
    const float* W = (ph == 0 ? Wl1 : Wr1);
    __syncthreads();
    #pragma unroll
    for (int i = 0; i < 8; i++) {  // stage 16x128 f32, coalesced
      int idx = t + i * 256;
      A_lds[idx] = A[idx];
    }
    __syncthreads();
    for (int k = 0; k < D_FEAT; k += 4) {
      float4 w[4];
      #pragma unroll
      for (int j = 0; j < 4; j++)
        w[j] = *(const float4*)(W + (size_t)(tx * 4 + j) * D_FEAT + k);
      #pragma unroll
      for (int i = 0; i < 4; i++) {
        float4 a = *(const float4*)(&A_lds[(ty * 4 + i) * D_FEAT + k]);  // wave-broadcast
        #pragma unroll
        for (int j = 0; j < 4; j++)
          acc[i][j] += a.x * w[j].x + a.y * w[j].y + a.z * w[j].z + a.w * w[j].w;
      }
    }
  }

  #pragma unroll
  for (int i = 0; i < 4; i++) {
    int row = m0 + ty * 4 + i;
    float v[4];
    #pragma unroll
    for (int j = 0; j < 4; j++) {
      float b = bl1[tx * 4 + j];
      float vv = acc[i][j] + b;
      v[j] = vv > 0.f ? vv : 0.f;
    }
    uint2 o; o.x = packbf(v[0], v[1]); o.y = packbf(v[2], v[3]);
    *(uint2*)(h + (size_t)row * HIDDEN + tx * 4) = o;
  }
}

// ---- kernel 6: layer-2 mean aggregation (gather), wave per node, bf16 ------
__global__ __launch_bounds__(256) void gather2_kernel(
    const u16* __restrict__ h, const int* __restrict__ offsets,
    const int* __restrict__ csr_src, u16* __restrict__ agg2) {
  const int node = blockIdx.x * 4 + (threadIdx.x >> 6);
  const int lane = threadIdx.x & 63;
  int b = offsets[node], e = offsets[node + 1];
  float a0 = 0.f, a1 = 0.f, a2 = 0.f, a3 = 0.f;
  for (int i = b; i < e; i++) {
    int s = csr_src[i];
    uint2 w = ((const uint2*)(h + (size_t)s * HIDDEN))[lane];
    a0 += bf_lo(w.x); a1 += bf_hi(w.x);
    a2 += bf_lo(w.y); a3 += bf_hi(w.y);
  }
  float inv = 1.0f / (float)max(e - b, 1);
  uint2 o;
  o.x = packbf(a0 * inv, a1 * inv);
  o.y = packbf(a2 * inv, a3 * inv);
  ((uint2*)(agg2 + (size_t)node * HIDDEN))[lane] = o;
}

// ---- kernel 7: layer-2 GEMM (VALU, f32) + bias + log_softmax, f32 out ------
// block = 16 rows; 256 thr; wave ty owns rows ty*4..ty*4+3, lane tx = col.
__global__ __launch_bounds__(256) void gemm2_kernel(
    const u16* __restrict__ agg2, const u16* __restrict__ h,
    const float* __restrict__ Wl2, const float* __restrict__ Wr2,
    const float* __restrict__ bl2, float* __restrict__ out) {
  __shared__ float A_lds[16 * 512];  // 32KB: [row][0..255]=agg2, [256..511]=h
  const int t  = threadIdx.x;
  const int tx = t & 63;
  const int ty = t >> 6;
  const int m0 = blockIdx.x * 16;

  #pragma unroll
  for (int i = 0; i < 8; i++) {  // 2048 u32 per source, coalesced
    int idx = t + i * 256;
    int r   = idx >> 7;     // 128 u32 per 256-bf16 row
    int kk  = idx & 127;
    u32 wa = ((const u32*)(agg2 + (size_t)(m0 + r) * HIDDEN))[kk];
    u32 wh = ((const u32*)(h    + (size_t)(m0 + r) * HIDDEN))[kk];
    A_lds[r * 512 + kk * 2]           = bf_lo(wa);
    A_lds[r * 512 + kk * 2 + 1]       = bf_hi(wa);
    A_lds[r * 512 + 256 + kk * 2]     = bf_lo(wh);
    A_lds[r * 512 + 256 + kk * 2 + 1] = bf_hi(wh);
  }
  __syncthreads();

  float acc[4] = {0.f, 0.f, 0.f, 0.f};
  const bool active = (tx < CLASSES);
  if (active) {
    for (int k = 0; k < HIDDEN; k += 4) {
      float4 w = *(const float4*)(Wl2 + (size_t)tx * HIDDEN + k);
      #pragma unroll
      for (int i = 0; i < 4; i++) {
        float4 a = *(const float4*)(&A_lds[(ty * 4 + i) * 512 + k]);
        acc[i] += a.x * w.x + a.y * w.y + a.z * w.z + a.w * w.w;
      }
    }
    for (int k = 0; k < HIDDEN; k += 4) {
      float4 w = *(const float4*)(Wr2 + (size_t)tx * HIDDEN + k);
      #pragma unroll
      for (int i = 0; i < 4; i++) {
        float4 a = *(const float4*)(&A_lds[(ty * 4 + i) * 512 + 256 + k]);
        acc[i] += a.x * w.x + a.y * w.y + a.z * w.z + a.w * w.w;
      }
    }
  }
  float bias = active ? bl2[tx] : 0.f;

  #pragma unroll
  for (int i = 0; i < 4; i++) {
    float v = acc[i] + bias;
    float mx = active ? v : -INFINITY;
    #pragma unroll
    for (int d = 1; d < 64; d <<= 1) mx = fmaxf(mx, __shfl_xor(mx, d, 64));
    float ex = active ? expf(v - mx) : 0.f;
    float s = ex;
    #pragma unroll
    for (int d = 1; d < 64; d <<= 1) s += __shfl_xor(s, d, 64);
    float l = mx + logf(s);
    if (active) {
      int row = m0 + ty * 4 + i;
      out[(size_t)row * CLASSES + tx] = v - l;
    }
  }
}

extern "C" void kernel_launch(void* const* d_in, const int* in_sizes, int n_in,
                              void* d_out, int out_size, void* d_ws, size_t ws_size,
                              hipStream_t stream) {
  const float* x   = (const float*)d_in[0];
  const void*  ei  = d_in[1];
  const float* Wl1 = (const float*)d_in[2];
  const float* bl1 = (const float*)d_in[3];
  const float* Wr1 = (const float*)d_in[4];
  const float* Wl2 = (const float*)d_in[5];
  const float* bl2 = (const float*)d_in[6];
  const float* Wr2 = (const float*)d_in[7];

  char* ws = (char*)d_ws;
  size_t off = 0;
  int* flag    = (int*)(ws + off); off += 256;
  int* src     = (int*)(ws + off); off += (size_t)N_EDGES * 4;             // 3.2MB
  int* dst     = (int*)(ws + off); off += (size_t)N_EDGES * 4;             // 3.2MB
  int* csr     = (int*)(ws + off); off += (size_t)N_EDGES * 4;             // 3.2MB
  int* counts  = (int*)(ws + off); off += 200192;
  int* offsets = (int*)(ws + off); off += 200192;
  int* cursor  = (int*)(ws + off); off += 200192;
  float* agg1  = (float*)(ws + off); off += (size_t)N_NODES * D_FEAT * 4;  // 25.6MB f32
  u16* hbuf    = (u16*)(ws + off);   off += (size_t)N_NODES * HIDDEN * 2;  // 25.6MB bf16
  u16* agg2    = (u16*)(ws + off);   off += (size_t)N_NODES * HIDDEN * 2;  // 25.6MB bf16

  hipMemsetAsync(counts, 0, (size_t)N_NODES * 4, stream);
  detect_kernel<<<1, 256, 0, stream>>>((const long long*)ei, flag);
  convert_hist_kernel<<<N_EDGES / 256, 256, 0, stream>>>(ei, flag, src, dst, counts);
  prefix_kernel<<<1, 1024, 0, stream>>>(counts, offsets, cursor);
  scatter_kernel<<<N_EDGES / 256, 256, 0, stream>>>(src, dst, cursor, csr);
  gather1_kernel<<<N_NODES / 4, 256, 0, stream>>>(x, offsets, csr, agg1);
  gemm1_kernel<<<N_NODES / 16, 256, 0, stream>>>(agg1, x, Wl1, Wr1, bl1, hbuf);
  gather2_kernel<<<N_NODES / 4, 256, 0, stream>>>(hbuf, offsets, csr, agg2);
  gemm2_kernel<<<N_NODES / 16, 256, 0, stream>>>(agg2, hbuf, Wl2, Wr2, bl2, (float*)d_out);
}